// Round 11
// baseline (328.675 us; speedup 1.0000x reference)
//
#include <hip/hip_runtime.h>
#include <hip/hip_bf16.h>
#include <cstdint>

#define B_ 4
#define T_ 2048
#define C_ 1024
#define H_ 16
#define D_ 64
#define M_ (B_*T_)   // 8192
#define N3 (3*C_)    // 3072

typedef __bf16 bf16;
typedef __bf16 bf16x8 __attribute__((ext_vector_type(8)));
typedef __bf16 bf16x4 __attribute__((ext_vector_type(4)));
typedef float  floatx4 __attribute__((ext_vector_type(4)));

// async global->LDS, 16B per lane; LDS dest = wave-uniform base + lane*16
__device__ __forceinline__ void gl_lds16(const bf16* g, bf16* l) {
  __builtin_amdgcn_global_load_lds(
      (__attribute__((address_space(1))) void*)(void*)g,
      (__attribute__((address_space(3))) void*)(void*)l,
      16, 0, 0);
}

// ---------------- cast fp32 -> bf16 ----------------
__global__ void cast_to_bf16(const float* __restrict__ in, bf16* __restrict__ out, int n) {
  int i = (blockIdx.x * blockDim.x + threadIdx.x) * 4;
  if (i < n) {
    const float4 f = *(const float4*)(in + i);
    bf16x4 o;
    o.x = (bf16)f.x; o.y = (bf16)f.y; o.z = (bf16)f.z; o.w = (bf16)f.w;
    *(bf16x4*)(out + i) = o;
  }
}

// ---------------- transpose + cast: in [R][C] fp32 -> out [C][R] bf16 ----------------
__global__ void transpose_cast(const float* __restrict__ in, bf16* __restrict__ out,
                               int R, int C) {
  __shared__ float tile[32][33];
  int r0 = blockIdx.y * 32, c0 = blockIdx.x * 32;
  int tx = threadIdx.x & 31, ty = threadIdx.x >> 5;  // 32x8
  #pragma unroll
  for (int j = 0; j < 32; j += 8)
    tile[ty + j][tx] = in[(size_t)(r0 + ty + j) * C + c0 + tx];
  __syncthreads();
  #pragma unroll
  for (int j = 0; j < 32; j += 8)
    out[(size_t)(c0 + ty + j) * R + r0 + tx] = (bf16)tile[tx][ty + j];
}

// ---------------- V [B,H,T,D] -> Vtp [B,H,D,T] with per-64 key permutation ----------
// slot s holds key(s) = (s&3) + 4*((s>>3)&3) + 16*((s>>2)&1) + 32*(s>>5): the attention
// PV A-fragment (in-register P) needs NO cross-lane exchange.
__global__ __launch_bounds__(256)
void transpose_v(const bf16* __restrict__ in, bf16* __restrict__ out) {
  __shared__ __attribute__((aligned(16))) bf16 tileN[64 * 64];
  const int tid = threadIdx.x;
  const int bh = blockIdx.z;
  const int t0 = blockIdx.x * 64;
  const int sk = tid >> 2, scc = tid & 3;
  {
    const bf16* p = in + ((size_t)bh * T_ + t0 + sk) * D_ + scc * 16;
    const bf16x8 r0 = *(const bf16x8*)p;
    const bf16x8 r1 = *(const bf16x8*)(p + 8);
    *(bf16x8*)(tileN + sk * 64 + ((2 * scc)     ^ (sk & 7)) * 8) = r0;
    *(bf16x8*)(tileN + sk * 64 + ((2 * scc + 1) ^ (sk & 7)) * 8) = r1;
  }
  __syncthreads();
  const int tc = (tid & 7) * 8;   // slot base
  #pragma unroll
  for (int half = 0; half < 2; half++) {
    const int d = (tid >> 3) + half * 32;
    bf16x8 o;
    #pragma unroll
    for (int j = 0; j < 8; j++) {
      const int slot = tc + j;
      const int row = (slot & 3) + 4 * ((slot >> 3) & 3) + 16 * ((slot >> 2) & 1)
                    + 32 * (slot >> 5);  // key for this slot
      o[j] = tileN[row * 64 + (((d >> 3) ^ (row & 7)) * 8) + (d & 7)];
    }
    *(bf16x8*)(out + ((size_t)bh * D_ + d) * T_ + t0 + tc) = o;
  }
}

// ---------------- legacy 128x128 GEMM (kept for the proj GEMM, N=1024) ----------------
template<int MODE>
__global__ __launch_bounds__(256)
void gemm_bt(const bf16* __restrict__ A, const bf16* __restrict__ Bt,
             const float* __restrict__ bias, float* __restrict__ out,
             bf16* __restrict__ qo, bf16* __restrict__ ko, bf16* __restrict__ vo,
             int M, int N, int K)
{
  __shared__ __attribute__((aligned(16))) bf16 As[128 * 32];
  __shared__ __attribute__((aligned(16))) bf16 Bs[128 * 32];

  const int tid  = threadIdx.x;
  const int w    = tid >> 6;
  const int lane = tid & 63;
  const int quad = lane >> 4;
  const int l16  = lane & 15;
  const int wm   = w & 1, wn = w >> 1;
  const int m0   = blockIdx.y * 128, n0 = blockIdx.x * 128;

  floatx4 acc[4][4] = {};

  const int lrow = lane >> 2;
  const int lk   = (lane & 3) * 8;

  const bf16* aptr = A  + (size_t)(m0 + w * 32 + lrow) * K + lk;
  const bf16* bptr = Bt + (size_t)(n0 + w * 32 + lrow) * K + lk;
  bf16* asl = As + w * 1024;
  bf16* bsl = Bs + w * 1024;

  for (int k0 = 0; k0 < K; k0 += 32) {
    gl_lds16(aptr,          asl);
    gl_lds16(aptr + 16 * K, asl + 512);
    gl_lds16(bptr,          bsl);
    gl_lds16(bptr + 16 * K, bsl + 512);
    aptr += 32; bptr += 32;
    __syncthreads();

    bf16x8 af[4], bfb[4];
    #pragma unroll
    for (int i = 0; i < 4; i++)
      af[i] = *(const bf16x8*)(As + (wm * 64 + i * 16 + l16) * 32 + quad * 8);
    #pragma unroll
    for (int i = 0; i < 4; i++)
      bfb[i] = *(const bf16x8*)(Bs + (wn * 64 + i * 16 + l16) * 32 + quad * 8);
    #pragma unroll
    for (int mi = 0; mi < 4; mi++)
      #pragma unroll
      for (int ni = 0; ni < 4; ni++)
        acc[mi][ni] = __builtin_amdgcn_mfma_f32_16x16x32_bf16(af[mi], bfb[ni], acc[mi][ni], 0, 0, 0);
    __syncthreads();
  }

  #pragma unroll
  for (int mi = 0; mi < 4; mi++) {
    #pragma unroll
    for (int ni = 0; ni < 4; ni++) {
      const int col = n0 + wn * 64 + ni * 16 + l16;
      const float bv = bias[col];
      #pragma unroll
      for (int r = 0; r < 4; r++) {
        const int row = m0 + wm * 64 + mi * 16 + quad * 4 + r;
        const float val = acc[mi][ni][r] + bv;
        if (MODE == 0) {
          const int b = row >> 11, t = row & 2047;
          const int s = col >> 10, c = col & 1023;
          const int h = c >> 6,  d = c & 63;
          bf16* dst = (s == 0) ? qo : (s == 1) ? ko : vo;
          dst[((size_t)(b * H_ + h) * T_ + t) * D_ + d] = (bf16)val;
        } else {
          out[(size_t)row * N + col] = val;
        }
      }
    }
  }
}

// ================= 256x256 8-phase GEMM (T2 swizzle + T3/T4 counted vmcnt + T5) =======
// (unchanged; see round-4 comments)
__device__ __forceinline__ void stage8(const bf16* g, int K, bf16* lds, int lane) {
  const int r = lane >> 3, s = (lane & 7) ^ r;   // inverse-swizzled global slot
  gl_lds16(g + (size_t)r * K + s * 8, lds);      // lds arg wave-uniform; HW adds lane*16B
}
__device__ __forceinline__ void stage_half(const bf16* g, int K, bf16* lds, int wv, int lane) {
  stage8(g + (size_t)(wv * 16) * K,     K, lds + (wv * 16) * 64, lane);
  stage8(g + (size_t)(wv * 16 + 8) * K, K, lds + (wv * 16 + 8) * 64, lane);
}

#define GBAR  __builtin_amdgcn_s_barrier()
#define WLGKM do { asm volatile("s_waitcnt lgkmcnt(0)"); __builtin_amdgcn_sched_barrier(0); } while (0)
#define WVM4  do { asm volatile("s_waitcnt vmcnt(4)");   __builtin_amdgcn_sched_barrier(0); } while (0)

template<int MODE>
__global__ __launch_bounds__(512, 2)
void gemm256(const bf16* __restrict__ A, const bf16* __restrict__ Bt,
             const float* __restrict__ bias, float* __restrict__ out,
             bf16* __restrict__ qo, bf16* __restrict__ ko, bf16* __restrict__ vo,
             int M, int N, int K)
{
  __shared__ __attribute__((aligned(16))) bf16 As[2][256 * 64];
  __shared__ __attribute__((aligned(16))) bf16 Bs[2][256 * 64];

  const int tid  = threadIdx.x;
  const int wv   = tid >> 6, lane = tid & 63;
  const int quad = lane >> 4, l16 = lane & 15;
  const int wm   = wv >> 2, wn = wv & 3;          // 2 x 4 wave grid
  const int NTT  = K >> 6;

  // T1 XCD swizzle
  const int nbx = gridDim.x;
  const int nwg = nbx * gridDim.y;
  const int bid = blockIdx.y * nbx + blockIdx.x;
  const int cpx = nwg >> 3;
  const int swz = (bid & 7) * cpx + (bid >> 3);
  const int n0  = (swz % nbx) * 256, m0 = (swz / nbx) * 256;

  floatx4 acc[8][4] = {};

  const bf16* Abase = A  + (size_t)m0 * K;
  const bf16* Bbase = Bt + (size_t)n0 * K;

  stage_half(Abase,                  K, As[0],            wv, lane);
  stage_half(Abase + (size_t)128*K,  K, As[0] + 128 * 64, wv, lane);
  stage_half(Bbase,                  K, Bs[0],            wv, lane);
  stage_half(Bbase + (size_t)128*K,  K, Bs[0] + 128 * 64, wv, lane);
  stage_half(Bbase + 64,             K, Bs[1],            wv, lane);
  stage_half(Abase + 64,             K, As[1],            wv, lane);
  WVM4;
  GBAR;

#define LOADA(qm)                                                          \
  _Pragma("unroll")                                                        \
  for (int mi = 0; mi < 4; mi++) {                                         \
    const int row = wm * 128 + (qm) * 64 + mi * 16 + l16;                  \
    const bf16* rp = bufA + row * 64;                                      \
    af[mi][0] = *(const bf16x8*)(rp + (( quad      ^ (row & 7)) * 8));     \
    af[mi][1] = *(const bf16x8*)(rp + (((4 | quad) ^ (row & 7)) * 8));     \
  }
#define LOADB(qn)                                                          \
  _Pragma("unroll")                                                        \
  for (int ni = 0; ni < 2; ni++) {                                         \
    const int row = wn * 64 + (qn) * 32 + ni * 16 + l16;                   \
    const bf16* rp = bufB + row * 64;                                      \
    bfr[(qn)*2+ni][0] = *(const bf16x8*)(rp + (( quad      ^ (row & 7)) * 8)); \
    bfr[(qn)*2+ni][1] = *(const bf16x8*)(rp + (((4 | quad) ^ (row & 7)) * 8)); \
  }
#define MM(qm, qn)                                                         \
  __builtin_amdgcn_s_setprio(1);                                           \
  _Pragma("unroll")                                                        \
  for (int mi = 0; mi < 4; mi++)                                           \
    _Pragma("unroll")                                                      \
    for (int ni = 0; ni < 2; ni++) {                                       \
      acc[(qm)*4+mi][(qn)*2+ni] = __builtin_amdgcn_mfma_f32_16x16x32_bf16( \
          af[mi][0], bfr[(qn)*2+ni][0], acc[(qm)*4+mi][(qn)*2+ni], 0, 0, 0); \
      acc[(qm)*4+mi][(qn)*2+ni] = __builtin_amdgcn_mfma_f32_16x16x32_bf16( \
          af[mi][1], bfr[(qn)*2+ni][1], acc[(qm)*4+mi][(qn)*2+ni], 0, 0, 0); \
    }                                                                      \
  __builtin_amdgcn_s_setprio(0);

  #pragma unroll 1
  for (int t = 0; t < NTT; t++) {
    const int cur = t & 1;
    const bf16* bufA = As[cur];
    const bf16* bufB = Bs[cur];
    bf16* nA = As[cur ^ 1];
    bf16* nB = Bs[cur ^ 1];
    bf16* cA = As[cur];
    bf16* cB = Bs[cur];
    const int kn1 = (t + 1) * 64, kn2 = (t + 2) * 64;
    const bool h1 = (t + 1 < NTT), h2 = (t + 2 < NTT);

    bf16x8 af[4][2], bfr[4][2];

    LOADA(0);
    LOADB(0);
    if (h1) stage_half(Abase + (size_t)128 * K + kn1, K, nA + 128 * 64, wv, lane);
    GBAR;
    WLGKM;
    MM(0, 0);
    GBAR;

    LOADB(1);
    if (h1) stage_half(Bbase + (size_t)128 * K + kn1, K, nB + 128 * 64, wv, lane);
    GBAR;
    WLGKM;
    MM(0, 1);
    GBAR;

    LOADA(1);
    if (h2) stage_half(Bbase + kn2, K, cB, wv, lane);
    GBAR;
    WLGKM;
    MM(1, 0);
    GBAR;

    if (h2) stage_half(Abase + kn2, K, cA, wv, lane);
    GBAR;
    MM(1, 1);
    WVM4;
    GBAR;
  }

#undef LOADA
#undef LOADB
#undef MM

  #pragma unroll
  for (int mi8 = 0; mi8 < 8; mi8++) {
    #pragma unroll
    for (int nf = 0; nf < 4; nf++) {
      const int col = n0 + wn * 64 + nf * 16 + l16;
      const float bv = bias[col];
      #pragma unroll
      for (int r = 0; r < 4; r++) {
        const int row = m0 + wm * 128 + mi8 * 16 + quad * 4 + r;
        const float val = acc[mi8][nf][r] + bv;
        if (MODE == 0) {
          const int b = row >> 11, tt = row & 2047;
          const int s = col >> 10, c = col & 1023;
          const int h = c >> 6, d = c & 63;
          bf16* dst = (s == 0) ? qo : (s == 1) ? ko : vo;
          dst[((size_t)(b * H_ + h) * T_ + tt) * D_ + d] = (bf16)val;
        } else {
          out[(size_t)row * N + col] = val;
        }
      }
    }
  }
}

// ---------------- flash attention: barrier-free, LDS-free ----------------
// R9 falsified the scheduling theory (split-K: occupancy stuck 19%, no gain). The
// residual coupling was the per-chunk rendezvous: every chunk all 4 waves drain
// their K/V prefetch (vmcnt->LDS publish) and meet at __syncthreads — the slowest
// wave's memory latency is imposed on all, every chunk. But all 4 waves read
// IDENTICAL K/V fragments, and the fragment pattern (16 rows x 64B) coalesces
// directly from global. So: load kf/vf straight global->VGPR (kf/vf were register-
// resident anyway; only the source changes), delete LDS/staging/barriers. Waves
// become independent streams; compiler counted-vmcnt pipelining overlaps chunk c+1
// loads with chunk c compute; redundant 4x reads hit L1/L2 (16KB/chunk, 512KB/bh
// << L3). SWAPPED QK^T + slot-permuted V keep softmax fully in-register.
// Grid (64 bh, 16 q-tiles), heavy-first (qt = 15 - blockIdx.y).
__global__ __launch_bounds__(256)
void attn_kernel(const bf16* __restrict__ Q, const bf16* __restrict__ Kp,
                 const bf16* __restrict__ Vtp, bf16* __restrict__ Y)
{
  const int tid  = threadIdx.x;
  const int w    = tid >> 6, lane = tid & 63;
  const int quad = lane >> 4, l16 = lane & 15;
  const int bh = blockIdx.x;
  const int b = bh >> 4, h = bh & 15;

  const float SC = 0.125f * 1.44269504088896f;  // 1/sqrt(D) * log2(e)

  const int qt = 15 - (int)blockIdx.y;   // heavy tiles dispatch first
  const int q0 = qt * 128;
  const int nch = 2 * qt + 2;

  bf16x8 qf[2][2];
  #pragma unroll
  for (int mt = 0; mt < 2; mt++) {
    const bf16* qp = Q + ((size_t)bh * T_ + q0 + mt * 64 + w * 16 + l16) * D_ + quad * 8;
    qf[mt][0] = *(const bf16x8*)qp;
    qf[mt][1] = *(const bf16x8*)(qp + 32);
  }

  floatx4 o[2][4] = {};
  float l_r[2] = {0.f, 0.f};

  // per-lane fragment base pointers (chunk stride: K += 64*D, V += 64)
  const bf16* kfp = Kp  + ((size_t)bh * T_ + l16) * D_ + quad * 8;
  const bf16* vfp = Vtp + ((size_t)bh * D_ + l16) * T_ + quad * 8;

  #pragma unroll 1
  for (int c = 0; c < nch; c++) {
    const int kv0 = c * 64;
    const bool act0 = (c < nch - 1);  // mt0 fully masked on last chunk

    // K fragments direct from global: kf[nt][j] = K[kv0+nt*16+l16][j*32+quad*8 ..+8]
    bf16x8 kf[4][2];
    #pragma unroll
    for (int nt = 0; nt < 4; nt++) {
      const bf16* kp = kfp + (size_t)nt * 16 * D_;
      kf[nt][0] = *(const bf16x8*)kp;
      kf[nt][1] = *(const bf16x8*)(kp + 32);
    }
    // V fragments direct from global (already slot-permuted):
    // vf[nt][kk] = Vtp[nt*16+l16][kv0 + kk*32 + quad*8 ..+8]
    bf16x8 vf[4][2];
    #pragma unroll
    for (int nt = 0; nt < 4; nt++) {
      const bf16* vp = vfp + (size_t)nt * 16 * T_;
      vf[nt][0] = *(const bf16x8*)vp;
      vf[nt][1] = *(const bf16x8*)(vp + 32);
    }
    kfp += 64 * D_;
    vfp += 64;

    // S^T = K Q^T (swapped): s[mt][nt][r] = score(key kv0+nt*16+quad*4+r, q ..+l16)
    floatx4 s[2][4];
    #pragma unroll
    for (int nt = 0; nt < 4; nt++) {
      if (act0) {
        floatx4 z = {};
        z = __builtin_amdgcn_mfma_f32_16x16x32_bf16(kf[nt][0], qf[0][0], z, 0, 0, 0);
        s[0][nt] = __builtin_amdgcn_mfma_f32_16x16x32_bf16(kf[nt][1], qf[0][1], z, 0, 0, 0);
      }
      floatx4 z = {};
      z = __builtin_amdgcn_mfma_f32_16x16x32_bf16(kf[nt][0], qf[1][0], z, 0, 0, 0);
      s[1][nt] = __builtin_amdgcn_mfma_f32_16x16x32_bf16(kf[nt][1], qf[1][1], z, 0, 0, 0);
    }

    #pragma unroll
    for (int mt = 0; mt < 2; mt++) {
      if (mt == 0 && !act0) continue;
      const bool diag = (c == 2 * qt + mt);
      const int qrow = q0 + mt * 64 + w * 16 + l16;   // lane's own query row
      float e[4][4];
      float ls0 = 0.f, ls1 = 0.f;
      #pragma unroll
      for (int nt = 0; nt < 4; nt++) {
        #pragma unroll
        for (int r = 0; r < 4; r++) {
          float x = s[mt][nt][r];
          if (diag) {
            if (kv0 + nt * 16 + quad * 4 + r > qrow) x = -1e30f;
          }
          const float ev = __builtin_amdgcn_exp2f(fmaf(x, SC, -8.f));
          e[nt][r] = ev;
          if (nt & 1) ls1 += ev; else ls0 += ev;
        }
      }
      l_r[mt] += ls0 + ls1;

      // pa[kk] element j = e[kk*2+(j>>2)][j&3]; pack via v_perm (high halves)
      union { uint32_t u[4]; bf16x8 v; } pa0, pa1;
      #pragma unroll
      for (int jj = 0; jj < 4; jj++) {
        pa0.u[jj] = __builtin_amdgcn_perm(
            __float_as_uint(e[(jj >> 1)][(jj & 1) * 2 + 1]),
            __float_as_uint(e[(jj >> 1)][(jj & 1) * 2]), 0x07060302u);
        pa1.u[jj] = __builtin_amdgcn_perm(
            __float_as_uint(e[2 + (jj >> 1)][(jj & 1) * 2 + 1]),
            __float_as_uint(e[2 + (jj >> 1)][(jj & 1) * 2]), 0x07060302u);
      }
      #pragma unroll
      for (int nt = 0; nt < 4; nt++) {
        o[mt][nt] = __builtin_amdgcn_mfma_f32_16x16x32_bf16(pa0.v, vf[nt][0], o[mt][nt], 0, 0, 0);
        o[mt][nt] = __builtin_amdgcn_mfma_f32_16x16x32_bf16(pa1.v, vf[nt][1], o[mt][nt], 0, 0, 0);
      }
    }
  }

  // epilogue: lane holds partial l for q = l16 (its quad's key subset);
  // xor-reduce across quads, then broadcast to the lanes that hold o rows.
  #pragma unroll
  for (int mt = 0; mt < 2; mt++) {
    float ls = l_r[mt];
    ls += __shfl_xor(ls, 16);
    ls += __shfl_xor(ls, 32);
    const float invls = 1.f / ls;      // full denominator for q = (group base + l16)
    #pragma unroll
    for (int r = 0; r < 4; r++) {
      const float inv = __shfl(invls, (lane & 48) + quad * 4 + r);
      const int t = q0 + mt * 64 + w * 16 + quad * 4 + r;
      #pragma unroll
      for (int nt = 0; nt < 4; nt++)
        Y[((size_t)b * T_ + t) * C_ + h * D_ + nt * 16 + l16] = (bf16)(o[mt][nt][r] * inv);
    }
  }
}

extern "C" void kernel_launch(void* const* d_in, const int* in_sizes, int n_in,
                              void* d_out, int out_size, void* d_ws, size_t ws_size,
                              hipStream_t stream)
{
  const float* x      = (const float*)d_in[0];
  const float* W_attn = (const float*)d_in[1];
  const float* b_attn = (const float*)d_in[2];
  const float* W_proj = (const float*)d_in[3];
  const float* b_proj = (const float*)d_in[4];
  float* out = (float*)d_out;

  bf16* xb  = (bf16*)d_ws;                  // [8192,1024]; reused as Vtp after gemm<0>
  bf16* wat = xb  + (size_t)M_ * C_;
  bf16* wpt = wat + (size_t)N3 * C_;
  bf16* qb  = wpt + (size_t)C_ * C_;
  bf16* kb  = qb  + (size_t)M_ * C_;
  bf16* vb  = kb  + (size_t)M_ * C_;
  bf16* yb  = vb  + (size_t)M_ * C_;
  bf16* vtb = xb;                           // [B,H,D,T] permuted

  cast_to_bf16<<<dim3(M_ * C_ / 1024), 256, 0, stream>>>(x, xb, M_ * C_);
  transpose_cast<<<dim3(N3 / 32, C_ / 32), 256, 0, stream>>>(W_attn, wat, C_, N3);
  transpose_cast<<<dim3(C_ / 32, C_ / 32), 256, 0, stream>>>(W_proj, wpt, C_, C_);
  gemm256<0><<<dim3(N3 / 256, M_ / 256), 512, 0, stream>>>(
      xb, wat, b_attn, nullptr, qb, kb, vb, M_, N3, C_);
  transpose_v<<<dim3(T_ / 64, 1, B_ * H_), 256, 0, stream>>>(vb, vtb);
  attn_kernel<<<dim3(B_ * H_, 16), 256, 0, stream>>>(qb, kb, vtb, yb);
  gemm_bt<1><<<dim3(C_ / 128, M_ / 128), 256, 0, stream>>>(
      yb, wpt, b_proj, out, nullptr, nullptr, nullptr, M_, C_, C_);
}

// Round 12
// 270.074 us; speedup vs baseline: 1.2170x; 1.2170x over previous
//
#include <hip/hip_runtime.h>
#include <hip/hip_bf16.h>
#include <cstdint>

#define B_ 4
#define T_ 2048
#define C_ 1024
#define H_ 16
#define D_ 64
#define M_ (B_*T_)   // 8192
#define N3 (3*C_)    // 3072

typedef __bf16 bf16;
typedef __bf16 bf16x8 __attribute__((ext_vector_type(8)));
typedef __bf16 bf16x4 __attribute__((ext_vector_type(4)));
typedef float  floatx4 __attribute__((ext_vector_type(4)));

// async global->LDS, 16B per lane; LDS dest = wave-uniform base + lane*16
__device__ __forceinline__ void gl_lds16(const bf16* g, bf16* l) {
  __builtin_amdgcn_global_load_lds(
      (__attribute__((address_space(1))) void*)(void*)g,
      (__attribute__((address_space(3))) void*)(void*)l,
      16, 0, 0);
}

// ---------------- cast fp32 -> bf16 ----------------
__global__ void cast_to_bf16(const float* __restrict__ in, bf16* __restrict__ out, int n) {
  int i = (blockIdx.x * blockDim.x + threadIdx.x) * 4;
  if (i < n) {
    const float4 f = *(const float4*)(in + i);
    bf16x4 o;
    o.x = (bf16)f.x; o.y = (bf16)f.y; o.z = (bf16)f.z; o.w = (bf16)f.w;
    *(bf16x4*)(out + i) = o;
  }
}

// ---------------- transpose + cast: in [R][C] fp32 -> out [C][R] bf16 ----------------
__global__ void transpose_cast(const float* __restrict__ in, bf16* __restrict__ out,
                               int R, int C) {
  __shared__ float tile[32][33];
  int r0 = blockIdx.y * 32, c0 = blockIdx.x * 32;
  int tx = threadIdx.x & 31, ty = threadIdx.x >> 5;  // 32x8
  #pragma unroll
  for (int j = 0; j < 32; j += 8)
    tile[ty + j][tx] = in[(size_t)(r0 + ty + j) * C + c0 + tx];
  __syncthreads();
  #pragma unroll
  for (int j = 0; j < 32; j += 8)
    out[(size_t)(c0 + ty + j) * R + r0 + tx] = (bf16)tile[tx][ty + j];
}

// ---------------- V [B,H,T,D] -> Vtp [B,H,D,T] with per-64 key permutation ----------
// slot s holds key(s) = (s&3) + 4*((s>>3)&3) + 16*((s>>2)&1) + 32*(s>>5): the attention
// PV A-fragment (in-register P) needs NO cross-lane exchange.
__global__ __launch_bounds__(256)
void transpose_v(const bf16* __restrict__ in, bf16* __restrict__ out) {
  __shared__ __attribute__((aligned(16))) bf16 tileN[64 * 64];
  const int tid = threadIdx.x;
  const int bh = blockIdx.z;
  const int t0 = blockIdx.x * 64;
  const int sk = tid >> 2, scc = tid & 3;
  {
    const bf16* p = in + ((size_t)bh * T_ + t0 + sk) * D_ + scc * 16;
    const bf16x8 r0 = *(const bf16x8*)p;
    const bf16x8 r1 = *(const bf16x8*)(p + 8);
    *(bf16x8*)(tileN + sk * 64 + ((2 * scc)     ^ (sk & 7)) * 8) = r0;
    *(bf16x8*)(tileN + sk * 64 + ((2 * scc + 1) ^ (sk & 7)) * 8) = r1;
  }
  __syncthreads();
  const int tc = (tid & 7) * 8;   // slot base
  #pragma unroll
  for (int half = 0; half < 2; half++) {
    const int d = (tid >> 3) + half * 32;
    bf16x8 o;
    #pragma unroll
    for (int j = 0; j < 8; j++) {
      const int slot = tc + j;
      const int row = (slot & 3) + 4 * ((slot >> 3) & 3) + 16 * ((slot >> 2) & 1)
                    + 32 * (slot >> 5);  // key for this slot
      o[j] = tileN[row * 64 + (((d >> 3) ^ (row & 7)) * 8) + (d & 7)];
    }
    *(bf16x8*)(out + ((size_t)bh * D_ + d) * T_ + t0 + tc) = o;
  }
}

// ---------------- legacy 128x128 GEMM (kept for the proj GEMM, N=1024) ----------------
template<int MODE>
__global__ __launch_bounds__(256)
void gemm_bt(const bf16* __restrict__ A, const bf16* __restrict__ Bt,
             const float* __restrict__ bias, float* __restrict__ out,
             bf16* __restrict__ qo, bf16* __restrict__ ko, bf16* __restrict__ vo,
             int M, int N, int K)
{
  __shared__ __attribute__((aligned(16))) bf16 As[128 * 32];
  __shared__ __attribute__((aligned(16))) bf16 Bs[128 * 32];

  const int tid  = threadIdx.x;
  const int w    = tid >> 6;
  const int lane = tid & 63;
  const int quad = lane >> 4;
  const int l16  = lane & 15;
  const int wm   = w & 1, wn = w >> 1;
  const int m0   = blockIdx.y * 128, n0 = blockIdx.x * 128;

  floatx4 acc[4][4] = {};

  const int lrow = lane >> 2;
  const int lk   = (lane & 3) * 8;

  const bf16* aptr = A  + (size_t)(m0 + w * 32 + lrow) * K + lk;
  const bf16* bptr = Bt + (size_t)(n0 + w * 32 + lrow) * K + lk;
  bf16* asl = As + w * 1024;
  bf16* bsl = Bs + w * 1024;

  for (int k0 = 0; k0 < K; k0 += 32) {
    gl_lds16(aptr,          asl);
    gl_lds16(aptr + 16 * K, asl + 512);
    gl_lds16(bptr,          bsl);
    gl_lds16(bptr + 16 * K, bsl + 512);
    aptr += 32; bptr += 32;
    __syncthreads();

    bf16x8 af[4], bfb[4];
    #pragma unroll
    for (int i = 0; i < 4; i++)
      af[i] = *(const bf16x8*)(As + (wm * 64 + i * 16 + l16) * 32 + quad * 8);
    #pragma unroll
    for (int i = 0; i < 4; i++)
      bfb[i] = *(const bf16x8*)(Bs + (wn * 64 + i * 16 + l16) * 32 + quad * 8);
    #pragma unroll
    for (int mi = 0; mi < 4; mi++)
      #pragma unroll
      for (int ni = 0; ni < 4; ni++)
        acc[mi][ni] = __builtin_amdgcn_mfma_f32_16x16x32_bf16(af[mi], bfb[ni], acc[mi][ni], 0, 0, 0);
    __syncthreads();
  }

  #pragma unroll
  for (int mi = 0; mi < 4; mi++) {
    #pragma unroll
    for (int ni = 0; ni < 4; ni++) {
      const int col = n0 + wn * 64 + ni * 16 + l16;
      const float bv = bias[col];
      #pragma unroll
      for (int r = 0; r < 4; r++) {
        const int row = m0 + wm * 64 + mi * 16 + quad * 4 + r;
        const float val = acc[mi][ni][r] + bv;
        if (MODE == 0) {
          const int b = row >> 11, t = row & 2047;
          const int s = col >> 10, c = col & 1023;
          const int h = c >> 6,  d = c & 63;
          bf16* dst = (s == 0) ? qo : (s == 1) ? ko : vo;
          dst[((size_t)(b * H_ + h) * T_ + t) * D_ + d] = (bf16)val;
        } else {
          out[(size_t)row * N + col] = val;
        }
      }
    }
  }
}

// ================= 256x256 8-phase GEMM (T2 swizzle + T3/T4 counted vmcnt + T5) =======
// (unchanged; see round-4 comments)
__device__ __forceinline__ void stage8(const bf16* g, int K, bf16* lds, int lane) {
  const int r = lane >> 3, s = (lane & 7) ^ r;   // inverse-swizzled global slot
  gl_lds16(g + (size_t)r * K + s * 8, lds);      // lds arg wave-uniform; HW adds lane*16B
}
__device__ __forceinline__ void stage_half(const bf16* g, int K, bf16* lds, int wv, int lane) {
  stage8(g + (size_t)(wv * 16) * K,     K, lds + (wv * 16) * 64, lane);
  stage8(g + (size_t)(wv * 16 + 8) * K, K, lds + (wv * 16 + 8) * 64, lane);
}

#define GBAR  __builtin_amdgcn_s_barrier()
#define WLGKM do { asm volatile("s_waitcnt lgkmcnt(0)"); __builtin_amdgcn_sched_barrier(0); } while (0)
#define WVM4  do { asm volatile("s_waitcnt vmcnt(4)");   __builtin_amdgcn_sched_barrier(0); } while (0)

template<int MODE>
__global__ __launch_bounds__(512, 2)
void gemm256(const bf16* __restrict__ A, const bf16* __restrict__ Bt,
             const float* __restrict__ bias, float* __restrict__ out,
             bf16* __restrict__ qo, bf16* __restrict__ ko, bf16* __restrict__ vo,
             int M, int N, int K)
{
  __shared__ __attribute__((aligned(16))) bf16 As[2][256 * 64];
  __shared__ __attribute__((aligned(16))) bf16 Bs[2][256 * 64];

  const int tid  = threadIdx.x;
  const int wv   = tid >> 6, lane = tid & 63;
  const int quad = lane >> 4, l16 = lane & 15;
  const int wm   = wv >> 2, wn = wv & 3;          // 2 x 4 wave grid
  const int NTT  = K >> 6;

  // T1 XCD swizzle
  const int nbx = gridDim.x;
  const int nwg = nbx * gridDim.y;
  const int bid = blockIdx.y * nbx + blockIdx.x;
  const int cpx = nwg >> 3;
  const int swz = (bid & 7) * cpx + (bid >> 3);
  const int n0  = (swz % nbx) * 256, m0 = (swz / nbx) * 256;

  floatx4 acc[8][4] = {};

  const bf16* Abase = A  + (size_t)m0 * K;
  const bf16* Bbase = Bt + (size_t)n0 * K;

  stage_half(Abase,                  K, As[0],            wv, lane);
  stage_half(Abase + (size_t)128*K,  K, As[0] + 128 * 64, wv, lane);
  stage_half(Bbase,                  K, Bs[0],            wv, lane);
  stage_half(Bbase + (size_t)128*K,  K, Bs[0] + 128 * 64, wv, lane);
  stage_half(Bbase + 64,             K, Bs[1],            wv, lane);
  stage_half(Abase + 64,             K, As[1],            wv, lane);
  WVM4;
  GBAR;

#define LOADA(qm)                                                          \
  _Pragma("unroll")                                                        \
  for (int mi = 0; mi < 4; mi++) {                                         \
    const int row = wm * 128 + (qm) * 64 + mi * 16 + l16;                  \
    const bf16* rp = bufA + row * 64;                                      \
    af[mi][0] = *(const bf16x8*)(rp + (( quad      ^ (row & 7)) * 8));     \
    af[mi][1] = *(const bf16x8*)(rp + (((4 | quad) ^ (row & 7)) * 8));     \
  }
#define LOADB(qn)                                                          \
  _Pragma("unroll")                                                        \
  for (int ni = 0; ni < 2; ni++) {                                         \
    const int row = wn * 64 + (qn) * 32 + ni * 16 + l16;                   \
    const bf16* rp = bufB + row * 64;                                      \
    bfr[(qn)*2+ni][0] = *(const bf16x8*)(rp + (( quad      ^ (row & 7)) * 8)); \
    bfr[(qn)*2+ni][1] = *(const bf16x8*)(rp + (((4 | quad) ^ (row & 7)) * 8)); \
  }
#define MM(qm, qn)                                                         \
  __builtin_amdgcn_s_setprio(1);                                           \
  _Pragma("unroll")                                                        \
  for (int mi = 0; mi < 4; mi++)                                           \
    _Pragma("unroll")                                                      \
    for (int ni = 0; ni < 2; ni++) {                                       \
      acc[(qm)*4+mi][(qn)*2+ni] = __builtin_amdgcn_mfma_f32_16x16x32_bf16( \
          af[mi][0], bfr[(qn)*2+ni][0], acc[(qm)*4+mi][(qn)*2+ni], 0, 0, 0); \
      acc[(qm)*4+mi][(qn)*2+ni] = __builtin_amdgcn_mfma_f32_16x16x32_bf16( \
          af[mi][1], bfr[(qn)*2+ni][1], acc[(qm)*4+mi][(qn)*2+ni], 0, 0, 0); \
    }                                                                      \
  __builtin_amdgcn_s_setprio(0);

  #pragma unroll 1
  for (int t = 0; t < NTT; t++) {
    const int cur = t & 1;
    const bf16* bufA = As[cur];
    const bf16* bufB = Bs[cur];
    bf16* nA = As[cur ^ 1];
    bf16* nB = Bs[cur ^ 1];
    bf16* cA = As[cur];
    bf16* cB = Bs[cur];
    const int kn1 = (t + 1) * 64, kn2 = (t + 2) * 64;
    const bool h1 = (t + 1 < NTT), h2 = (t + 2 < NTT);

    bf16x8 af[4][2], bfr[4][2];

    LOADA(0);
    LOADB(0);
    if (h1) stage_half(Abase + (size_t)128 * K + kn1, K, nA + 128 * 64, wv, lane);
    GBAR;
    WLGKM;
    MM(0, 0);
    GBAR;

    LOADB(1);
    if (h1) stage_half(Bbase + (size_t)128 * K + kn1, K, nB + 128 * 64, wv, lane);
    GBAR;
    WLGKM;
    MM(0, 1);
    GBAR;

    LOADA(1);
    if (h2) stage_half(Bbase + kn2, K, cB, wv, lane);
    GBAR;
    WLGKM;
    MM(1, 0);
    GBAR;

    if (h2) stage_half(Abase + kn2, K, cA, wv, lane);
    GBAR;
    MM(1, 1);
    WVM4;
    GBAR;
  }

#undef LOADA
#undef LOADB
#undef MM

  #pragma unroll
  for (int mi8 = 0; mi8 < 8; mi8++) {
    #pragma unroll
    for (int nf = 0; nf < 4; nf++) {
      const int col = n0 + wn * 64 + nf * 16 + l16;
      const float bv = bias[col];
      #pragma unroll
      for (int r = 0; r < 4; r++) {
        const int row = m0 + wm * 128 + mi8 * 16 + quad * 4 + r;
        const float val = acc[mi8][nf][r] + bv;
        if (MODE == 0) {
          const int b = row >> 11, tt = row & 2047;
          const int s = col >> 10, c = col & 1023;
          const int h = c >> 6, d = c & 63;
          bf16* dst = (s == 0) ? qo : (s == 1) ? ko : vo;
          dst[((size_t)(b * H_ + h) * T_ + tt) * D_ + d] = (bf16)val;
        } else {
          out[(size_t)row * N + col] = val;
        }
      }
    }
  }
}

// ---------------- flash attention (round-8 structure restored + T5 setprio) ----------
// R11 refuted barrier-free direct-global loads (135 us: unhidden L2 latency each
// chunk — no compiler cross-iteration pipelining). The R8 LDS double-buffer +
// register-prefetch (issue-early/write-late, T14) IS the latency-hiding mechanism;
// restored verbatim. NEW this round: s_setprio(1) around QK and PV MFMA clusters —
// at 4 independent blocks/CU the co-resident blocks are phase-diverse (m191 regime,
// +4-7% attn), unlike lockstep single-block GEMM (m190 null).
// SWAPPED QK^T: lane owns query q=l16; V slot-permuted so PV A-frag is the lane's
// own keys -> softmax fully in-register. Grid (64 bh, 16 q-tiles), heavy-first.
__global__ __launch_bounds__(256)
void attn_kernel(const bf16* __restrict__ Q, const bf16* __restrict__ Kp,
                 const bf16* __restrict__ Vtp, bf16* __restrict__ Y)
{
  __shared__ __attribute__((aligned(16))) bf16 Ks[2][64 * 72];  // [key][d]
  __shared__ __attribute__((aligned(16))) bf16 Vs[2][64 * 72];  // [d][slot]

  const int tid  = threadIdx.x;
  const int w    = tid >> 6, lane = tid & 63;
  const int quad = lane >> 4, l16 = lane & 15;
  const int bh = blockIdx.x;
  const int b = bh >> 4, h = bh & 15;

  const int sk = tid >> 2;          // staging row (key for K, d for V)
  const int sc = (tid & 3) * 16;    // staging 32B segment

  const float SC = 0.125f * 1.44269504088896f;  // 1/sqrt(D) * log2(e)

  const int qt = 15 - (int)blockIdx.y;   // heavy tiles dispatch first
  const int q0 = qt * 128;
  const int nch = 2 * qt + 2;

  bf16x8 qf[2][2];
  #pragma unroll
  for (int mt = 0; mt < 2; mt++) {
    const bf16* qp = Q + ((size_t)bh * T_ + q0 + mt * 64 + w * 16 + l16) * D_ + quad * 8;
    qf[mt][0] = *(const bf16x8*)qp;
    qf[mt][1] = *(const bf16x8*)(qp + 32);
  }

  floatx4 o[2][4] = {};
  float l_r[2] = {0.f, 0.f};

  const bf16* kpp = Kp  + (size_t)bh * T_ * D_ + (size_t)sk * D_ + sc;
  const bf16* vpp = Vtp + (size_t)bh * D_ * T_ + (size_t)sk * T_ + sc;

  {
    const bf16x8 k0 = *(const bf16x8*)kpp, k1 = *(const bf16x8*)(kpp + 8);
    const bf16x8 v0 = *(const bf16x8*)vpp, v1 = *(const bf16x8*)(vpp + 8);
    bf16* kd = Ks[0] + sk * 72 + sc;
    *(bf16x8*)kd = k0; *(bf16x8*)(kd + 8) = k1;
    bf16* vd = Vs[0] + sk * 72 + sc;
    *(bf16x8*)vd = v0; *(bf16x8*)(vd + 8) = v1;
    kpp += 64 * D_; vpp += 64;
  }
  __syncthreads();

  #pragma unroll 1
  for (int c = 0; c < nch; c++) {
    const int cur = c & 1;

    bf16x8 nk0, nk1, nv0, nv1;
    const bool have = (c + 1 < nch);
    if (have) {
      nk0 = *(const bf16x8*)kpp; nk1 = *(const bf16x8*)(kpp + 8);
      nv0 = *(const bf16x8*)vpp; nv1 = *(const bf16x8*)(vpp + 8);
      kpp += 64 * D_; vpp += 64;
    }

    const bf16* KsC = Ks[cur];
    const bf16* VsC = Vs[cur];
    const int kv0 = c * 64;
    const bool act0 = (c < nch - 1);  // mt0 fully masked on last chunk

    // S^T = K Q^T (swapped): s[mt][nt][r] = score(key kv0+nt*16+quad*4+r, q ..+l16)
    floatx4 s[2][4];
    __builtin_amdgcn_s_setprio(1);
    #pragma unroll
    for (int nt = 0; nt < 4; nt++) {
      const bf16x8 kf0 = *(const bf16x8*)(KsC + (nt * 16 + l16) * 72 + quad * 8);
      const bf16x8 kf1 = *(const bf16x8*)(KsC + (nt * 16 + l16) * 72 + 32 + quad * 8);
      if (act0) {
        floatx4 z = {};
        z = __builtin_amdgcn_mfma_f32_16x16x32_bf16(kf0, qf[0][0], z, 0, 0, 0);
        s[0][nt] = __builtin_amdgcn_mfma_f32_16x16x32_bf16(kf1, qf[0][1], z, 0, 0, 0);
      }
      floatx4 z = {};
      z = __builtin_amdgcn_mfma_f32_16x16x32_bf16(kf0, qf[1][0], z, 0, 0, 0);
      s[1][nt] = __builtin_amdgcn_mfma_f32_16x16x32_bf16(kf1, qf[1][1], z, 0, 0, 0);
    }
    __builtin_amdgcn_s_setprio(0);

    bf16x8 vfr[4][2];
    #pragma unroll
    for (int nt = 0; nt < 4; nt++) {
      vfr[nt][0] = *(const bf16x8*)(VsC + (nt * 16 + l16) * 72 + quad * 8);
      vfr[nt][1] = *(const bf16x8*)(VsC + (nt * 16 + l16) * 72 + 32 + quad * 8);
    }

    #pragma unroll
    for (int mt = 0; mt < 2; mt++) {
      if (mt == 0 && !act0) continue;
      const bool diag = (c == 2 * qt + mt);
      const int qrow = q0 + mt * 64 + w * 16 + l16;   // lane's own query row
      float e[4][4];
      float ls0 = 0.f, ls1 = 0.f;
      #pragma unroll
      for (int nt = 0; nt < 4; nt++) {
        #pragma unroll
        for (int r = 0; r < 4; r++) {
          float x = s[mt][nt][r];
          if (diag) {
            if (kv0 + nt * 16 + quad * 4 + r > qrow) x = -1e30f;
          }
          const float ev = __builtin_amdgcn_exp2f(fmaf(x, SC, -8.f));
          e[nt][r] = ev;
          if (nt & 1) ls1 += ev; else ls0 += ev;
        }
      }
      l_r[mt] += ls0 + ls1;

      // pa[kk] element j = e[kk*2+(j>>2)][j&3]; pack via v_perm (high halves)
      union { uint32_t u[4]; bf16x8 v; } pa0, pa1;
      #pragma unroll
      for (int jj = 0; jj < 4; jj++) {
        pa0.u[jj] = __builtin_amdgcn_perm(
            __float_as_uint(e[(jj >> 1)][(jj & 1) * 2 + 1]),
            __float_as_uint(e[(jj >> 1)][(jj & 1) * 2]), 0x07060302u);
        pa1.u[jj] = __builtin_amdgcn_perm(
            __float_as_uint(e[2 + (jj >> 1)][(jj & 1) * 2 + 1]),
            __float_as_uint(e[2 + (jj >> 1)][(jj & 1) * 2]), 0x07060302u);
      }
      __builtin_amdgcn_s_setprio(1);
      #pragma unroll
      for (int nt = 0; nt < 4; nt++) {
        o[mt][nt] = __builtin_amdgcn_mfma_f32_16x16x32_bf16(pa0.v, vfr[nt][0], o[mt][nt], 0, 0, 0);
        o[mt][nt] = __builtin_amdgcn_mfma_f32_16x16x32_bf16(pa1.v, vfr[nt][1], o[mt][nt], 0, 0, 0);
      }
      __builtin_amdgcn_s_setprio(0);
    }

    if (have) {
      bf16* kd = Ks[cur ^ 1] + sk * 72 + sc;
      *(bf16x8*)kd = nk0; *(bf16x8*)(kd + 8) = nk1;
      bf16* vd = Vs[cur ^ 1] + sk * 72 + sc;
      *(bf16x8*)vd = nv0; *(bf16x8*)(vd + 8) = nv1;
    }
    __syncthreads();
  }

  // epilogue: lane holds partial l for q = l16 (its quad's key subset);
  // xor-reduce across quads, then broadcast to the lanes that hold o rows.
  #pragma unroll
  for (int mt = 0; mt < 2; mt++) {
    float ls = l_r[mt];
    ls += __shfl_xor(ls, 16);
    ls += __shfl_xor(ls, 32);
    const float invls = 1.f / ls;      // full denominator for q = (group base + l16)
    #pragma unroll
    for (int r = 0; r < 4; r++) {
      const float inv = __shfl(invls, (lane & 48) + quad * 4 + r);
      const int t = q0 + mt * 64 + w * 16 + quad * 4 + r;
      #pragma unroll
      for (int nt = 0; nt < 4; nt++)
        Y[((size_t)b * T_ + t) * C_ + h * D_ + nt * 16 + l16] = (bf16)(o[mt][nt][r] * inv);
    }
  }
}

extern "C" void kernel_launch(void* const* d_in, const int* in_sizes, int n_in,
                              void* d_out, int out_size, void* d_ws, size_t ws_size,
                              hipStream_t stream)
{
  const float* x      = (const float*)d_in[0];
  const float* W_attn = (const float*)d_in[1];
  const float* b_attn = (const float*)d_in[2];
  const float* W_proj = (const float*)d_in[3];
  const float* b_proj = (const float*)d_in[4];
  float* out = (float*)d_out;

  bf16* xb  = (bf16*)d_ws;                  // [8192,1024]; reused as Vtp after gemm<0>
  bf16* wat = xb  + (size_t)M_ * C_;
  bf16* wpt = wat + (size_t)N3 * C_;
  bf16* qb  = wpt + (size_t)C_ * C_;
  bf16* kb  = qb  + (size_t)M_ * C_;
  bf16* vb  = kb  + (size_t)M_ * C_;
  bf16* yb  = vb  + (size_t)M_ * C_;
  bf16* vtb = xb;                           // [B,H,D,T] permuted

  cast_to_bf16<<<dim3(M_ * C_ / 1024), 256, 0, stream>>>(x, xb, M_ * C_);
  transpose_cast<<<dim3(N3 / 32, C_ / 32), 256, 0, stream>>>(W_attn, wat, C_, N3);
  transpose_cast<<<dim3(C_ / 32, C_ / 32), 256, 0, stream>>>(W_proj, wpt, C_, C_);
  gemm256<0><<<dim3(N3 / 256, M_ / 256), 512, 0, stream>>>(
      xb, wat, b_attn, nullptr, qb, kb, vb, M_, N3, C_);
  transpose_v<<<dim3(T_ / 64, 1, B_ * H_), 256, 0, stream>>>(vb, vtb);
  attn_kernel<<<dim3(B_ * H_, 16), 256, 0, stream>>>(qb, kb, vtb, yb);
  gemm_bt<1><<<dim3(C_ / 128, M_ / 128), 256, 0, stream>>>(
      yb, wpt, b_proj, out, nullptr, nullptr, nullptr, M_, C_, C_);
}

// Round 13
// 267.133 us; speedup vs baseline: 1.2304x; 1.0110x over previous
//
#include <hip/hip_runtime.h>
#include <hip/hip_bf16.h>
#include <cstdint>

#define B_ 4
#define T_ 2048
#define C_ 1024
#define H_ 16
#define D_ 64
#define M_ (B_*T_)   // 8192
#define N3 (3*C_)    // 3072

typedef __bf16 bf16;
typedef __bf16 bf16x8 __attribute__((ext_vector_type(8)));
typedef __bf16 bf16x4 __attribute__((ext_vector_type(4)));
typedef float  floatx4 __attribute__((ext_vector_type(4)));

// async global->LDS, 16B per lane; LDS dest = wave-uniform base + lane*16
__device__ __forceinline__ void gl_lds16(const bf16* g, bf16* l) {
  __builtin_amdgcn_global_load_lds(
      (__attribute__((address_space(1))) void*)(void*)g,
      (__attribute__((address_space(3))) void*)(void*)l,
      16, 0, 0);
}

// ---------------- cast fp32 -> bf16 ----------------
__global__ void cast_to_bf16(const float* __restrict__ in, bf16* __restrict__ out, int n) {
  int i = (blockIdx.x * blockDim.x + threadIdx.x) * 4;
  if (i < n) {
    const float4 f = *(const float4*)(in + i);
    bf16x4 o;
    o.x = (bf16)f.x; o.y = (bf16)f.y; o.z = (bf16)f.z; o.w = (bf16)f.w;
    *(bf16x4*)(out + i) = o;
  }
}

// ---------------- transpose + cast: in [R][C] fp32 -> out [C][R] bf16 ----------------
__global__ void transpose_cast(const float* __restrict__ in, bf16* __restrict__ out,
                               int R, int C) {
  __shared__ float tile[32][33];
  int r0 = blockIdx.y * 32, c0 = blockIdx.x * 32;
  int tx = threadIdx.x & 31, ty = threadIdx.x >> 5;  // 32x8
  #pragma unroll
  for (int j = 0; j < 32; j += 8)
    tile[ty + j][tx] = in[(size_t)(r0 + ty + j) * C + c0 + tx];
  __syncthreads();
  #pragma unroll
  for (int j = 0; j < 32; j += 8)
    out[(size_t)(c0 + ty + j) * R + r0 + tx] = (bf16)tile[tx][ty + j];
}

// ---------------- V [B,H,T,D] -> Vtp [B,H,D,T] with per-64 key permutation ----------
// slot s holds key(s) = (s&3) + 4*((s>>3)&3) + 16*((s>>2)&1) + 32*(s>>5): the attention
// PV A-fragment (in-register P) needs NO cross-lane exchange.
__global__ __launch_bounds__(256)
void transpose_v(const bf16* __restrict__ in, bf16* __restrict__ out) {
  __shared__ __attribute__((aligned(16))) bf16 tileN[64 * 64];
  const int tid = threadIdx.x;
  const int bh = blockIdx.z;
  const int t0 = blockIdx.x * 64;
  const int sk = tid >> 2, scc = tid & 3;
  {
    const bf16* p = in + ((size_t)bh * T_ + t0 + sk) * D_ + scc * 16;
    const bf16x8 r0 = *(const bf16x8*)p;
    const bf16x8 r1 = *(const bf16x8*)(p + 8);
    *(bf16x8*)(tileN + sk * 64 + ((2 * scc)     ^ (sk & 7)) * 8) = r0;
    *(bf16x8*)(tileN + sk * 64 + ((2 * scc + 1) ^ (sk & 7)) * 8) = r1;
  }
  __syncthreads();
  const int tc = (tid & 7) * 8;   // slot base
  #pragma unroll
  for (int half = 0; half < 2; half++) {
    const int d = (tid >> 3) + half * 32;
    bf16x8 o;
    #pragma unroll
    for (int j = 0; j < 8; j++) {
      const int slot = tc + j;
      const int row = (slot & 3) + 4 * ((slot >> 3) & 3) + 16 * ((slot >> 2) & 1)
                    + 32 * (slot >> 5);  // key for this slot
      o[j] = tileN[row * 64 + (((d >> 3) ^ (row & 7)) * 8) + (d & 7)];
    }
    *(bf16x8*)(out + ((size_t)bh * D_ + d) * T_ + t0 + tc) = o;
  }
}

// ---------------- legacy 128x128 GEMM (kept for the proj GEMM, N=1024) ----------------
template<int MODE>
__global__ __launch_bounds__(256)
void gemm_bt(const bf16* __restrict__ A, const bf16* __restrict__ Bt,
             const float* __restrict__ bias, float* __restrict__ out,
             bf16* __restrict__ qo, bf16* __restrict__ ko, bf16* __restrict__ vo,
             int M, int N, int K)
{
  __shared__ __attribute__((aligned(16))) bf16 As[128 * 32];
  __shared__ __attribute__((aligned(16))) bf16 Bs[128 * 32];

  const int tid  = threadIdx.x;
  const int w    = tid >> 6;
  const int lane = tid & 63;
  const int quad = lane >> 4;
  const int l16  = lane & 15;
  const int wm   = w & 1, wn = w >> 1;
  const int m0   = blockIdx.y * 128, n0 = blockIdx.x * 128;

  floatx4 acc[4][4] = {};

  const int lrow = lane >> 2;
  const int lk   = (lane & 3) * 8;

  const bf16* aptr = A  + (size_t)(m0 + w * 32 + lrow) * K + lk;
  const bf16* bptr = Bt + (size_t)(n0 + w * 32 + lrow) * K + lk;
  bf16* asl = As + w * 1024;
  bf16* bsl = Bs + w * 1024;

  for (int k0 = 0; k0 < K; k0 += 32) {
    gl_lds16(aptr,          asl);
    gl_lds16(aptr + 16 * K, asl + 512);
    gl_lds16(bptr,          bsl);
    gl_lds16(bptr + 16 * K, bsl + 512);
    aptr += 32; bptr += 32;
    __syncthreads();

    bf16x8 af[4], bfb[4];
    #pragma unroll
    for (int i = 0; i < 4; i++)
      af[i] = *(const bf16x8*)(As + (wm * 64 + i * 16 + l16) * 32 + quad * 8);
    #pragma unroll
    for (int i = 0; i < 4; i++)
      bfb[i] = *(const bf16x8*)(Bs + (wn * 64 + i * 16 + l16) * 32 + quad * 8);
    #pragma unroll
    for (int mi = 0; mi < 4; mi++)
      #pragma unroll
      for (int ni = 0; ni < 4; ni++)
        acc[mi][ni] = __builtin_amdgcn_mfma_f32_16x16x32_bf16(af[mi], bfb[ni], acc[mi][ni], 0, 0, 0);
    __syncthreads();
  }

  #pragma unroll
  for (int mi = 0; mi < 4; mi++) {
    #pragma unroll
    for (int ni = 0; ni < 4; ni++) {
      const int col = n0 + wn * 64 + ni * 16 + l16;
      const float bv = bias[col];
      #pragma unroll
      for (int r = 0; r < 4; r++) {
        const int row = m0 + wm * 64 + mi * 16 + quad * 4 + r;
        const float val = acc[mi][ni][r] + bv;
        if (MODE == 0) {
          const int b = row >> 11, t = row & 2047;
          const int s = col >> 10, c = col & 1023;
          const int h = c >> 6,  d = c & 63;
          bf16* dst = (s == 0) ? qo : (s == 1) ? ko : vo;
          dst[((size_t)(b * H_ + h) * T_ + t) * D_ + d] = (bf16)val;
        } else {
          out[(size_t)row * N + col] = val;
        }
      }
    }
  }
}

// ========== 256x128 2-phase GEMM for QKV (T2 swizzle + counted vmcnt + T5) ==========
// R12 diagnosis: 256x256 tile = 384 blocks at 128KB LDS = 1 block/CU = 1.5 dispatch
// rounds -> 75% packing (occupancy 17% ~= 25%*0.68). Retile BM=256 x BN=128: grid
// 24x32 = 768 = EXACTLY 3x256 (full packing all rounds), LDS 96KB, 8 waves (2Mx4N,
// per-wave 128x32, acc[8][2]), 2 phases/K-tile of 16 MFMA (barrier rate halved).
// Stage unit = 64-row quarter (1 gl_lds16/thread; wave wv covers rows wv*8..+7).
// ph0 reads cur A rows {0-63}u{128-191} (frag mi 0-3 for both wm) + all B;
// ph1 reads cur A rows {64-127}u{192-255} (mi 4-7).
// Stage schedule (race-free; all writes barrier-separated from region's readers):
//   ph0: stage (t+1).{A1,A3,B0,B1} -> nxt    ph1: stage (t+2).{A0,A2} -> cur
// Boundary vmcnt(2): only (t+2).{A0,A2} (newest) may remain -> all t+1 resident.
// Prologue: t0 all 6 quarters, t1.{A0,A2}, vmcnt(2) (mimics steady state).
// Swizzle (rule 21): physical 16B slot = logical ^ (row&7); linear LDS dest +
// inverse-swizzled global source (stage8) + swizzled ds_read.

__device__ __forceinline__ void stage8(const bf16* g, int K, bf16* lds, int lane) {
  const int r = lane >> 3, s = (lane & 7) ^ r;   // inverse-swizzled global slot
  gl_lds16(g + (size_t)r * K + s * 8, lds);      // lds arg wave-uniform; HW adds lane*16B
}
// one 64-row quarter: wave wv stages rows wv*8 .. wv*8+7 (1 load/thread)
__device__ __forceinline__ void stage_q(const bf16* g, int K, bf16* lds, int wv, int lane) {
  stage8(g + (size_t)(wv * 8) * K, K, lds + (wv * 8) * 64, lane);
}

#define GBAR  __builtin_amdgcn_s_barrier()
#define WLGKM do { asm volatile("s_waitcnt lgkmcnt(0)"); __builtin_amdgcn_sched_barrier(0); } while (0)
#define WVM2  do { asm volatile("s_waitcnt vmcnt(2)");   __builtin_amdgcn_sched_barrier(0); } while (0)

__global__ __launch_bounds__(512, 2)
void gemm_qkv(const bf16* __restrict__ A, const bf16* __restrict__ Bt,
              const float* __restrict__ bias,
              bf16* __restrict__ qo, bf16* __restrict__ ko, bf16* __restrict__ vo,
              int M, int N, int K)
{
  __shared__ __attribute__((aligned(16))) bf16 As[2][256 * 64];  // 64KB
  __shared__ __attribute__((aligned(16))) bf16 Bs[2][128 * 64];  // 32KB

  const int tid  = threadIdx.x;
  const int wv   = tid >> 6, lane = tid & 63;
  const int quad = lane >> 4, l16 = lane & 15;
  const int wm   = wv >> 2, wn = wv & 3;          // 2 x 4 wave grid
  const int NTT  = K >> 6;

  // T1 XCD swizzle: 768 blocks = 8 * 96
  const int nbx = gridDim.x;                      // 24
  const int bid = blockIdx.y * nbx + blockIdx.x;
  const int cpx = (nbx * gridDim.y) >> 3;         // 96
  const int swz = (bid & 7) * cpx + (bid >> 3);
  const int n0  = (swz % nbx) * 128, m0 = (swz / nbx) * 256;

  floatx4 acc[8][2] = {};

  const bf16* Abase = A  + (size_t)m0 * K;
  const bf16* Bbase = Bt + (size_t)n0 * K;

  // prologue: t0 all 6 quarters (oldest), then t1.{A0,A2}; vmcnt(2)
  stage_q(Abase,                    K, As[0],            wv, lane);  // t0.A0
  stage_q(Abase + (size_t)128*K,    K, As[0] + 128 * 64, wv, lane);  // t0.A2
  stage_q(Abase + (size_t) 64*K,    K, As[0] +  64 * 64, wv, lane);  // t0.A1
  stage_q(Abase + (size_t)192*K,    K, As[0] + 192 * 64, wv, lane);  // t0.A3
  stage_q(Bbase,                    K, Bs[0],            wv, lane);  // t0.B0
  stage_q(Bbase + (size_t) 64*K,    K, Bs[0] +  64 * 64, wv, lane);  // t0.B1
  stage_q(Abase + 64,               K, As[1],            wv, lane);  // t1.A0
  stage_q(Abase + (size_t)128*K+64, K, As[1] + 128 * 64, wv, lane);  // t1.A2
  WVM2;
  GBAR;

#define LOADA(ph)                                                          \
  _Pragma("unroll")                                                        \
  for (int mi = 0; mi < 4; mi++) {                                         \
    const int row = wm * 128 + (ph) * 64 + mi * 16 + l16;                  \
    const bf16* rp = bufA + row * 64;                                      \
    af[mi][0] = *(const bf16x8*)(rp + (( quad      ^ (row & 7)) * 8));     \
    af[mi][1] = *(const bf16x8*)(rp + (((4 | quad) ^ (row & 7)) * 8));     \
  }
#define LOADB                                                              \
  _Pragma("unroll")                                                        \
  for (int ni = 0; ni < 2; ni++) {                                         \
    const int row = wn * 32 + ni * 16 + l16;                               \
    const bf16* rp = bufB + row * 64;                                      \
    bfr[ni][0] = *(const bf16x8*)(rp + (( quad      ^ (row & 7)) * 8));    \
    bfr[ni][1] = *(const bf16x8*)(rp + (((4 | quad) ^ (row & 7)) * 8));    \
  }
#define MM(ph)                                                             \
  __builtin_amdgcn_s_setprio(1);                                           \
  _Pragma("unroll")                                                        \
  for (int mi = 0; mi < 4; mi++)                                           \
    _Pragma("unroll")                                                      \
    for (int ni = 0; ni < 2; ni++) {                                       \
      acc[(ph)*4+mi][ni] = __builtin_amdgcn_mfma_f32_16x16x32_bf16(        \
          af[mi][0], bfr[ni][0], acc[(ph)*4+mi][ni], 0, 0, 0);             \
      acc[(ph)*4+mi][ni] = __builtin_amdgcn_mfma_f32_16x16x32_bf16(        \
          af[mi][1], bfr[ni][1], acc[(ph)*4+mi][ni], 0, 0, 0);             \
    }                                                                      \
  __builtin_amdgcn_s_setprio(0);

  #pragma unroll 1
  for (int t = 0; t < NTT; t++) {
    const int cur = t & 1;
    const bf16* bufA = As[cur];
    const bf16* bufB = Bs[cur];
    bf16* nA = As[cur ^ 1];   // tile t+1
    bf16* nB = Bs[cur ^ 1];
    bf16* cA = As[cur];       // tile t+2 reuses cur as regions retire
    const int kn1 = (t + 1) * 64, kn2 = (t + 2) * 64;
    const bool h1 = (t + 1 < NTT), h2 = (t + 2 < NTT);

    bf16x8 af[4][2], bfr[2][2];

    // ---- ph0: read A{Q0,Q2 frags} + B; stage (t+1).{A1,A3,B0,B1} -> nxt ----
    LOADA(0);
    LOADB;
    if (h1) {
      stage_q(Abase + (size_t) 64*K + kn1, K, nA +  64 * 64, wv, lane);
      stage_q(Abase + (size_t)192*K + kn1, K, nA + 192 * 64, wv, lane);
      stage_q(Bbase + kn1,                 K, nB,            wv, lane);
      stage_q(Bbase + (size_t) 64*K + kn1, K, nB +  64 * 64, wv, lane);
    }
    GBAR;
    WLGKM;
    MM(0);
    GBAR;

    // ---- ph1: read A{Q1,Q3 frags}; stage (t+2).{A0,A2} -> cur (retired) ----
    LOADA(1);
    if (h2) {
      stage_q(Abase + kn2,                 K, cA,            wv, lane);
      stage_q(Abase + (size_t)128*K + kn2, K, cA + 128 * 64, wv, lane);
    }
    GBAR;
    WLGKM;
    MM(1);
    WVM2;
    GBAR;
  }

#undef LOADA
#undef LOADB
#undef MM

  // epilogue: scatter to Q/K/V [B,H,T,D]
  #pragma unroll
  for (int mi8 = 0; mi8 < 8; mi8++) {
    #pragma unroll
    for (int nf = 0; nf < 2; nf++) {
      const int col = n0 + wn * 32 + nf * 16 + l16;
      const float bv = bias[col];
      #pragma unroll
      for (int r = 0; r < 4; r++) {
        const int row = m0 + wm * 128 + mi8 * 16 + quad * 4 + r;
        const float val = acc[mi8][nf][r] + bv;
        const int b = row >> 11, tt = row & 2047;
        const int s = col >> 10, c = col & 1023;
        const int h = c >> 6, d = c & 63;
        bf16* dst = (s == 0) ? qo : (s == 1) ? ko : vo;
        dst[((size_t)(b * H_ + h) * T_ + tt) * D_ + d] = (bf16)val;
      }
    }
  }
}

// ---------------- flash attention (R8 structure + T5 setprio; unchanged) ----------
__global__ __launch_bounds__(256)
void attn_kernel(const bf16* __restrict__ Q, const bf16* __restrict__ Kp,
                 const bf16* __restrict__ Vtp, bf16* __restrict__ Y)
{
  __shared__ __attribute__((aligned(16))) bf16 Ks[2][64 * 72];  // [key][d]
  __shared__ __attribute__((aligned(16))) bf16 Vs[2][64 * 72];  // [d][slot]

  const int tid  = threadIdx.x;
  const int w    = tid >> 6, lane = tid & 63;
  const int quad = lane >> 4, l16 = lane & 15;
  const int bh = blockIdx.x;
  const int b = bh >> 4, h = bh & 15;

  const int sk = tid >> 2;          // staging row (key for K, d for V)
  const int sc = (tid & 3) * 16;    // staging 32B segment

  const float SC = 0.125f * 1.44269504088896f;  // 1/sqrt(D) * log2(e)

  const int qt = 15 - (int)blockIdx.y;   // heavy tiles dispatch first
  const int q0 = qt * 128;
  const int nch = 2 * qt + 2;

  bf16x8 qf[2][2];
  #pragma unroll
  for (int mt = 0; mt < 2; mt++) {
    const bf16* qp = Q + ((size_t)bh * T_ + q0 + mt * 64 + w * 16 + l16) * D_ + quad * 8;
    qf[mt][0] = *(const bf16x8*)qp;
    qf[mt][1] = *(const bf16x8*)(qp + 32);
  }

  floatx4 o[2][4] = {};
  float l_r[2] = {0.f, 0.f};

  const bf16* kpp = Kp  + (size_t)bh * T_ * D_ + (size_t)sk * D_ + sc;
  const bf16* vpp = Vtp + (size_t)bh * D_ * T_ + (size_t)sk * T_ + sc;

  {
    const bf16x8 k0 = *(const bf16x8*)kpp, k1 = *(const bf16x8*)(kpp + 8);
    const bf16x8 v0 = *(const bf16x8*)vpp, v1 = *(const bf16x8*)(vpp + 8);
    bf16* kd = Ks[0] + sk * 72 + sc;
    *(bf16x8*)kd = k0; *(bf16x8*)(kd + 8) = k1;
    bf16* vd = Vs[0] + sk * 72 + sc;
    *(bf16x8*)vd = v0; *(bf16x8*)(vd + 8) = v1;
    kpp += 64 * D_; vpp += 64;
  }
  __syncthreads();

  #pragma unroll 1
  for (int c = 0; c < nch; c++) {
    const int cur = c & 1;

    bf16x8 nk0, nk1, nv0, nv1;
    const bool have = (c + 1 < nch);
    if (have) {
      nk0 = *(const bf16x8*)kpp; nk1 = *(const bf16x8*)(kpp + 8);
      nv0 = *(const bf16x8*)vpp; nv1 = *(const bf16x8*)(vpp + 8);
      kpp += 64 * D_; vpp += 64;
    }

    const bf16* KsC = Ks[cur];
    const bf16* VsC = Vs[cur];
    const int kv0 = c * 64;
    const bool act0 = (c < nch - 1);  // mt0 fully masked on last chunk

    // S^T = K Q^T (swapped): s[mt][nt][r] = score(key kv0+nt*16+quad*4+r, q ..+l16)
    floatx4 s[2][4];
    __builtin_amdgcn_s_setprio(1);
    #pragma unroll
    for (int nt = 0; nt < 4; nt++) {
      const bf16x8 kf0 = *(const bf16x8*)(KsC + (nt * 16 + l16) * 72 + quad * 8);
      const bf16x8 kf1 = *(const bf16x8*)(KsC + (nt * 16 + l16) * 72 + 32 + quad * 8);
      if (act0) {
        floatx4 z = {};
        z = __builtin_amdgcn_mfma_f32_16x16x32_bf16(kf0, qf[0][0], z, 0, 0, 0);
        s[0][nt] = __builtin_amdgcn_mfma_f32_16x16x32_bf16(kf1, qf[0][1], z, 0, 0, 0);
      }
      floatx4 z = {};
      z = __builtin_amdgcn_mfma_f32_16x16x32_bf16(kf0, qf[1][0], z, 0, 0, 0);
      s[1][nt] = __builtin_amdgcn_mfma_f32_16x16x32_bf16(kf1, qf[1][1], z, 0, 0, 0);
    }
    __builtin_amdgcn_s_setprio(0);

    bf16x8 vfr[4][2];
    #pragma unroll
    for (int nt = 0; nt < 4; nt++) {
      vfr[nt][0] = *(const bf16x8*)(VsC + (nt * 16 + l16) * 72 + quad * 8);
      vfr[nt][1] = *(const bf16x8*)(VsC + (nt * 16 + l16) * 72 + 32 + quad * 8);
    }

    #pragma unroll
    for (int mt = 0; mt < 2; mt++) {
      if (mt == 0 && !act0) continue;
      const bool diag = (c == 2 * qt + mt);
      const int qrow = q0 + mt * 64 + w * 16 + l16;   // lane's own query row
      float e[4][4];
      float ls0 = 0.f, ls1 = 0.f;
      #pragma unroll
      for (int nt = 0; nt < 4; nt++) {
        #pragma unroll
        for (int r = 0; r < 4; r++) {
          float x = s[mt][nt][r];
          if (diag) {
            if (kv0 + nt * 16 + quad * 4 + r > qrow) x = -1e30f;
          }
          const float ev = __builtin_amdgcn_exp2f(fmaf(x, SC, -8.f));
          e[nt][r] = ev;
          if (nt & 1) ls1 += ev; else ls0 += ev;
        }
      }
      l_r[mt] += ls0 + ls1;

      // pa[kk] element j = e[kk*2+(j>>2)][j&3]; pack via v_perm (high halves)
      union { uint32_t u[4]; bf16x8 v; } pa0, pa1;
      #pragma unroll
      for (int jj = 0; jj < 4; jj++) {
        pa0.u[jj] = __builtin_amdgcn_perm(
            __float_as_uint(e[(jj >> 1)][(jj & 1) * 2 + 1]),
            __float_as_uint(e[(jj >> 1)][(jj & 1) * 2]), 0x07060302u);
        pa1.u[jj] = __builtin_amdgcn_perm(
            __float_as_uint(e[2 + (jj >> 1)][(jj & 1) * 2 + 1]),
            __float_as_uint(e[2 + (jj >> 1)][(jj & 1) * 2]), 0x07060302u);
      }
      __builtin_amdgcn_s_setprio(1);
      #pragma unroll
      for (int nt = 0; nt < 4; nt++) {
        o[mt][nt] = __builtin_amdgcn_mfma_f32_16x16x32_bf16(pa0.v, vfr[nt][0], o[mt][nt], 0, 0, 0);
        o[mt][nt] = __builtin_amdgcn_mfma_f32_16x16x32_bf16(pa1.v, vfr[nt][1], o[mt][nt], 0, 0, 0);
      }
      __builtin_amdgcn_s_setprio(0);
    }

    if (have) {
      bf16* kd = Ks[cur ^ 1] + sk * 72 + sc;
      *(bf16x8*)kd = nk0; *(bf16x8*)(kd + 8) = nk1;
      bf16* vd = Vs[cur ^ 1] + sk * 72 + sc;
      *(bf16x8*)vd = nv0; *(bf16x8*)(vd + 8) = nv1;
    }
    __syncthreads();
  }

  // epilogue
  #pragma unroll
  for (int mt = 0; mt < 2; mt++) {
    float ls = l_r[mt];
    ls += __shfl_xor(ls, 16);
    ls += __shfl_xor(ls, 32);
    const float invls = 1.f / ls;
    #pragma unroll
    for (int r = 0; r < 4; r++) {
      const float inv = __shfl(invls, (lane & 48) + quad * 4 + r);
      const int t = q0 + mt * 64 + w * 16 + quad * 4 + r;
      #pragma unroll
      for (int nt = 0; nt < 4; nt++)
        Y[((size_t)b * T_ + t) * C_ + h * D_ + nt * 16 + l16] = (bf16)(o[mt][nt][r] * inv);
    }
  }
}

extern "C" void kernel_launch(void* const* d_in, const int* in_sizes, int n_in,
                              void* d_out, int out_size, void* d_ws, size_t ws_size,
                              hipStream_t stream)
{
  const float* x      = (const float*)d_in[0];
  const float* W_attn = (const float*)d_in[1];
  const float* b_attn = (const float*)d_in[2];
  const float* W_proj = (const float*)d_in[3];
  const float* b_proj = (const float*)d_in[4];
  float* out = (float*)d_out;

  bf16* xb  = (bf16*)d_ws;                  // [8192,1024]; reused as Vtp after gemm_qkv
  bf16* wat = xb  + (size_t)M_ * C_;
  bf16* wpt = wat + (size_t)N3 * C_;
  bf16* qb  = wpt + (size_t)C_ * C_;
  bf16* kb  = qb  + (size_t)M_ * C_;
  bf16* vb  = kb  + (size_t)M_ * C_;
  bf16* yb  = vb  + (size_t)M_ * C_;
  bf16* vtb = xb;                           // [B,H,D,T] permuted

  cast_to_bf16<<<dim3(M_ * C_ / 1024), 256, 0, stream>>>(x, xb, M_ * C_);
  transpose_cast<<<dim3(N3 / 32, C_ / 32), 256, 0, stream>>>(W_attn, wat, C_, N3);
  transpose_cast<<<dim3(C_ / 32, C_ / 32), 256, 0, stream>>>(W_proj, wpt, C_, C_);
  gemm_qkv<<<dim3(N3 / 128, M_ / 256), 512, 0, stream>>>(
      xb, wat, b_attn, qb, kb, vb, M_, N3, C_);
  transpose_v<<<dim3(T_ / 64, 1, B_ * H_), 256, 0, stream>>>(vb, vtb);
  attn_kernel<<<dim3(B_ * H_, 16), 256, 0, stream>>>(qb, kb, vtb, yb);
  gemm_bt<1><<<dim3(C_ / 128, M_ / 128), 256, 0, stream>>>(
      yb, wpt, b_proj, out, nullptr, nullptr, nullptr, M_, C_, C_);
}